// Round 2
// baseline (2511.090 us; speedup 1.0000x reference)
//
#include <hip/hip_runtime.h>
#include <math.h>

// MoE gate: logits = x @ W^T ; softmax ; top-8 (idx, weight), sorted desc.
// x: [T, 2048] fp32, W: [64, 2048] fp32.
// Output (all float32): d_out[0 .. T*8) = topk_idx (as float), d_out[T*8 .. 2*T*8) = topk_weight
//
// v2: LDS-staged GEMM. W k-chunk (64x128 = 32KB) double-buffered in LDS,
// XOR-swizzled (f ^= ((e>>2)&7)<<2) so the 16 expert-group ds_read_b128
// pattern is bank-conflict-free. Thread = 2 tokens x 4 experts.

constexpr int H = 2048;
constexpr int E = 64;
constexpr int TOPK = 8;
constexpr int CK = 128;            // k-chunk
constexpr int NCHUNK = H / CK;     // 16
constexpr int TOK_BLK = 32;        // tokens per block

__global__ __launch_bounds__(256, 2)
void moe_gate_kernel(const float* __restrict__ x, const float* __restrict__ w,
                     float* __restrict__ out, int T) {
    __shared__ float wlds[2][E * CK];        // 2 x 32 KB, swizzled
    __shared__ float lg[TOK_BLK][E + 1];     // logits, stride 65 (conflict-free)

    const int tid = threadIdx.x;
    const int eg  = tid & 15;        // expert group: experts eg*4 .. eg*4+3
    const int tsl = tid >> 4;        // token slot 0..15
    const int tok0 = blockIdx.x * TOK_BLK + tsl * 2;

    const float* __restrict__ xr0 = x + (size_t)tok0 * H;
    const float* __restrict__ xr1 = xr0 + H;

    // staging: thread loads row se, floats [sf0 + 4u), u=0..7 (8 x float4)
    const int se    = tid >> 2;                  // 0..63 (4 threads/row)
    const int sf0   = (tid & 3) * 32;            // bits >= 5
    const int smask = ((se >> 2) & 7) << 2;      // swizzle mask (bits 2..4)
    const float* __restrict__ wsrc = w + (size_t)se * H + sf0;
    float* const wdst0 = &wlds[0][se * CK + sf0];
    float* const wdst1 = &wlds[1][se * CK + sf0];

    float acc0[4] = {0.f, 0.f, 0.f, 0.f};
    float acc1[4] = {0.f, 0.f, 0.f, 0.f};

    // prologue: stage chunk 0 into buf 0
    float4 wreg[8];
    #pragma unroll
    for (int u = 0; u < 8; ++u)
        wreg[u] = *reinterpret_cast<const float4*>(wsrc + 4 * u);
    #pragma unroll
    for (int u = 0; u < 8; ++u)
        *reinterpret_cast<float4*>(wdst0 + ((4 * u) ^ smask)) = wreg[u];

    const int ebase = (eg * 4) * CK;
    const int rmask = (eg & 7) << 2;    // == ((e>>2)&7)<<2 for e = eg*4+j, j<4

    for (int c = 0; c < NCHUNK; ++c) {
        __syncthreads();   // buf (c&1) fully written; prev readers done
        // prefetch next W chunk into regs (in flight during compute)
        if (c + 1 < NCHUNK) {
            const float* ws2 = wsrc + (c + 1) * CK;
            #pragma unroll
            for (int u = 0; u < 8; ++u)
                wreg[u] = *reinterpret_cast<const float4*>(ws2 + 4 * u);
        }
        const float* __restrict__ wl  = wlds[c & 1];
        const float* __restrict__ xc0 = xr0 + c * CK;
        const float* __restrict__ xc1 = xr1 + c * CK;

        #pragma unroll
        for (int s = 0; s < CK; s += 16) {
            float4 xa[4], xb[4];
            #pragma unroll
            for (int v = 0; v < 4; ++v) {
                xa[v] = *reinterpret_cast<const float4*>(xc0 + s + 4 * v);
                xb[v] = *reinterpret_cast<const float4*>(xc1 + s + 4 * v);
            }
            #pragma unroll
            for (int v = 0; v < 4; ++v) {
                const int kx = (s + 4 * v) ^ rmask;
                #pragma unroll
                for (int j = 0; j < 4; ++j) {
                    const float4 wv = *reinterpret_cast<const float4*>(wl + ebase + j * CK + kx);
                    acc0[j] = fmaf(xa[v].x, wv.x, acc0[j]);
                    acc0[j] = fmaf(xa[v].y, wv.y, acc0[j]);
                    acc0[j] = fmaf(xa[v].z, wv.z, acc0[j]);
                    acc0[j] = fmaf(xa[v].w, wv.w, acc0[j]);
                    acc1[j] = fmaf(xb[v].x, wv.x, acc1[j]);
                    acc1[j] = fmaf(xb[v].y, wv.y, acc1[j]);
                    acc1[j] = fmaf(xb[v].z, wv.z, acc1[j]);
                    acc1[j] = fmaf(xb[v].w, wv.w, acc1[j]);
                }
            }
        }
        // write prefetched chunk into the other buffer (not being read)
        if (c + 1 < NCHUNK) {
            float* wd = (c & 1) ? wdst0 : wdst1;
            #pragma unroll
            for (int u = 0; u < 8; ++u)
                *reinterpret_cast<float4*>(wd + ((4 * u) ^ smask)) = wreg[u];
        }
    }

    // stash logits
    #pragma unroll
    for (int j = 0; j < 4; ++j) {
        lg[tsl * 2 + 0][eg * 4 + j] = acc0[j];
        lg[tsl * 2 + 1][eg * 4 + j] = acc1[j];
    }
    __syncthreads();

    // per-token softmax + top-8 (one thread per token; overlapped by other block on CU)
    if (tid < TOK_BLK) {
        const int t = blockIdx.x * TOK_BLK + tid;
        float* lrow = lg[tid];

        float m = lrow[0];
        for (int i = 1; i < E; ++i) m = fmaxf(m, lrow[i]);
        float ssum = 0.f;
        for (int i = 0; i < E; ++i) ssum += expf(lrow[i] - m);

        float* __restrict__ oidx = out + (size_t)t * TOPK;
        float* __restrict__ ow   = out + (size_t)T * TOPK + (size_t)t * TOPK;

        for (int p = 0; p < TOPK; ++p) {
            float best = -INFINITY; int bi = 0;
            for (int i = 0; i < E; ++i) {
                float v = lrow[i];
                if (v > best) { best = v; bi = i; }   // strict >: ties -> lowest index
            }
            oidx[p] = (float)bi;
            ow[p]   = expf(best - m) / ssum;
            lrow[bi] = -INFINITY;
        }
    }
}

extern "C" void kernel_launch(void* const* d_in, const int* in_sizes, int n_in,
                              void* d_out, int out_size, void* d_ws, size_t ws_size,
                              hipStream_t stream) {
    const float* x = (const float*)d_in[0];
    const float* w = (const float*)d_in[1];
    float* out = (float*)d_out;
    const int T = in_sizes[0] / H;                    // 16384
    const int grid = T / TOK_BLK;                     // 512
    hipLaunchKernelGGL(moe_gate_kernel, dim3(grid), dim3(256), 0, stream,
                       x, w, out, T);
}

// Round 6
// 297.324 us; speedup vs baseline: 8.4456x; 8.4456x over previous
//
#include <hip/hip_runtime.h>
#include <math.h>

// MoE gate: logits = x @ W^T ; softmax ; top-8 (idx, weight), sorted desc.
// x: [T, 2048] fp32, W: [64, 2048] fp32.
// Output (all float32): d_out[0 .. T*8) = topk_idx (as float), d_out[T*8 .. 2*T*8) = topk_weight
//
// v3: double-buffered LDS for BOTH W and x chunks. Staging = 6 float4 regs
// (24 VGPR live), linear conflict-free ds_writes, read-side XOR swizzle
// folded into the PRE-SWIZZLED GLOBAL SOURCE address. One barrier per chunk.
// Thread = 2 tokens x 4 experts.

constexpr int H = 2048;
constexpr int E = 64;
constexpr int TOPK = 8;
constexpr int CK = 64;           // k-chunk (floats)
constexpr int NCH = H / CK;      // 32
constexpr int TOK_BLK = 32;

// LDS float layout (12288 floats = 48 KB):
//  [0     .. 4096)  W buf0: float idx e*64 + 4*f4 + i  holds w[e][k0 + 4*(f4 ^ ((e>>2)&7)) + i]
//  [4096  .. 8192)  W buf1
//  [8192  ..10240)  X buf0: float idx r*64 + 4*f4 + i  holds x[t0+r][k0 + 4*(f4 ^ ((r>>1)&3)) + i]
//  [10240 ..12288)  X buf1
//  epilogue overlay [0..2080): lg[32][65]

__global__ __launch_bounds__(256, 2)
void moe_gate_kernel(const float* __restrict__ x, const float* __restrict__ w,
                     float* __restrict__ out, int T) {
    __shared__ float smem[12288];
    const int tid = threadIdx.x;
    const int eg  = tid & 15;        // expert group: experts eg*4 .. eg*4+3
    const int tsl = tid >> 4;        // token slot 0..15 -> tokens tsl*2, tsl*2+1

    // ---- staging sources (pre-swizzled global addresses) ----
    const float* wsrc[4];
    #pragma unroll
    for (int u = 0; u < 4; ++u) {
        const int s  = u * 256 + tid;       // f4-slot 0..1023
        const int e  = s >> 4;              // 0..63
        const int f4 = s & 15;
        wsrc[u] = w + (size_t)e * H + 4 * (f4 ^ ((e >> 2) & 7));
    }
    const float* xsrc[2];
    #pragma unroll
    for (int u = 0; u < 2; ++u) {
        const int s  = u * 256 + tid;       // 0..511
        const int r  = s >> 4;              // 0..31
        const int f4 = s & 15;
        xsrc[u] = x + (size_t)(blockIdx.x * TOK_BLK + r) * H + 4 * (f4 ^ ((r >> 1) & 3));
    }

    // ---- prologue: stage chunk 0 into buf 0 ----
    float4 stw[4], stx[2];
    #pragma unroll
    for (int u = 0; u < 4; ++u) stw[u] = *reinterpret_cast<const float4*>(wsrc[u]);
    #pragma unroll
    for (int u = 0; u < 2; ++u) stx[u] = *reinterpret_cast<const float4*>(xsrc[u]);
    #pragma unroll
    for (int u = 0; u < 4; ++u)
        *reinterpret_cast<float4*>(smem + 4 * (u * 256 + tid)) = stw[u];
    #pragma unroll
    for (int u = 0; u < 2; ++u)
        *reinterpret_cast<float4*>(smem + 8192 + 4 * (u * 256 + tid)) = stx[u];

    float acc0[4] = {0.f, 0.f, 0.f, 0.f};
    float acc1[4] = {0.f, 0.f, 0.f, 0.f};
    const int wc = eg & 7;       // W read xor const (f4 units)
    const int xc = tsl & 3;      // X read xor const

    for (int c = 0; c < NCH; ++c) {
        __syncthreads();                   // buf (c&1) ready; buf^1 free
        const int p = c & 1;
        // issue next chunk's global loads (hidden under compute)
        if (c + 1 < NCH) {
            const int k0 = (c + 1) * CK;
            #pragma unroll
            for (int u = 0; u < 4; ++u) stw[u] = *reinterpret_cast<const float4*>(wsrc[u] + k0);
            #pragma unroll
            for (int u = 0; u < 2; ++u) stx[u] = *reinterpret_cast<const float4*>(xsrc[u] + k0);
        }
        const float* wb = smem + p * 4096 + eg * 256;          // + j*64 + fw
        const float* xr = smem + 8192 + p * 2048 + tsl * 128;  // rows tsl*2, tsl*2+1

        #pragma unroll 4
        for (int kq = 0; kq < 16; ++kq) {
            const int fw = (kq ^ wc) << 2;
            const int fx = (kq ^ xc) << 2;
            const float4 xa  = *reinterpret_cast<const float4*>(xr + fx);
            const float4 xb2 = *reinterpret_cast<const float4*>(xr + 64 + fx);
            #pragma unroll
            for (int j = 0; j < 4; ++j) {
                const float4 wv = *reinterpret_cast<const float4*>(wb + j * 64 + fw);
                acc0[j] = fmaf(xa.x,  wv.x, acc0[j]);
                acc0[j] = fmaf(xa.y,  wv.y, acc0[j]);
                acc0[j] = fmaf(xa.z,  wv.z, acc0[j]);
                acc0[j] = fmaf(xa.w,  wv.w, acc0[j]);
                acc1[j] = fmaf(xb2.x, wv.x, acc1[j]);
                acc1[j] = fmaf(xb2.y, wv.y, acc1[j]);
                acc1[j] = fmaf(xb2.z, wv.z, acc1[j]);
                acc1[j] = fmaf(xb2.w, wv.w, acc1[j]);
            }
        }
        // write staged regs into the buffer NOT being read (linear, conflict-free)
        if (c + 1 < NCH) {
            float* wd = smem + (p ^ 1) * 4096;
            float* xd = smem + 8192 + (p ^ 1) * 2048;
            #pragma unroll
            for (int u = 0; u < 4; ++u)
                *reinterpret_cast<float4*>(wd + 4 * (u * 256 + tid)) = stw[u];
            #pragma unroll
            for (int u = 0; u < 2; ++u)
                *reinterpret_cast<float4*>(xd + 4 * (u * 256 + tid)) = stx[u];
        }
    }

    // ---- epilogue: logits -> LDS overlay (Wbuf0 region, no longer read) ----
    __syncthreads();
    #pragma unroll
    for (int j = 0; j < 4; ++j) {
        smem[(tsl * 2 + 0) * 65 + eg * 4 + j] = acc0[j];
        smem[(tsl * 2 + 1) * 65 + eg * 4 + j] = acc1[j];
    }
    __syncthreads();

    if (tid < TOK_BLK) {
        const int t = blockIdx.x * TOK_BLK + tid;
        float* lrow = smem + tid * 65;

        float m = lrow[0];
        for (int i = 1; i < E; ++i) m = fmaxf(m, lrow[i]);
        float ssum = 0.f;
        for (int i = 0; i < E; ++i) ssum += expf(lrow[i] - m);

        float* __restrict__ oidx = out + (size_t)t * TOPK;
        float* __restrict__ ow   = out + (size_t)T * TOPK + (size_t)t * TOPK;

        for (int p = 0; p < TOPK; ++p) {
            float best = -INFINITY; int bi = 0;
            for (int i = 0; i < E; ++i) {
                float v = lrow[i];
                if (v > best) { best = v; bi = i; }   // strict >: ties -> lowest index
            }
            oidx[p] = (float)bi;
            ow[p]   = expf(best - m) / ssum;
            lrow[bi] = -INFINITY;
        }
    }
}

extern "C" void kernel_launch(void* const* d_in, const int* in_sizes, int n_in,
                              void* d_out, int out_size, void* d_ws, size_t ws_size,
                              hipStream_t stream) {
    const float* x = (const float*)d_in[0];
    const float* w = (const float*)d_in[1];
    float* out = (float*)d_out;
    const int T = in_sizes[0] / H;                    // 16384
    const int grid = T / TOK_BLK;                     // 512
    hipLaunchKernelGGL(moe_gate_kernel, dim3(grid), dim3(256), 0, stream,
                       x, w, out, T);
}